// Round 1
// baseline (302.342 us; speedup 1.0000x reference)
//
#include <hip/hip_runtime.h>
#include <hip/hip_bf16.h>
#include <stdint.h>

#define B_SZ 8192
#define D_SZ 1024
#define O_SZ 1024
#define E_SZ 8

#define BM 256
#define BN 128
#define BK 64
#define NT 128  // virtual K-steps: E_SZ * (D_SZ / BK)

typedef __bf16 bf16_t;
typedef __bf16 bf16x8 __attribute__((ext_vector_type(8)));
typedef __bf16 bf16x4 __attribute__((ext_vector_type(4)));
typedef float  f32x4  __attribute__((ext_vector_type(4)));

// ---------------- gating: softmax(x @ Wg + bg) fused with x fp32->bf16 ----------------
__global__ __launch_bounds__(256) void gating_cvt_kernel(
    const float* __restrict__ x, const float* __restrict__ Wg,
    const float* __restrict__ bg, float* __restrict__ gates,
    bf16_t* __restrict__ xb) {
  const int w = threadIdx.x >> 6, lane = threadIdx.x & 63;
  const int b = blockIdx.x * 4 + w;
  const float4* xr = (const float4*)(x + (size_t)b * D_SZ);
  bf16x4* xbr = (bf16x4*)(xb + (size_t)b * D_SZ);
  float acc[8];
#pragma unroll
  for (int e = 0; e < 8; ++e) acc[e] = 0.f;
#pragma unroll 1
  for (int it = 0; it < 4; ++it) {
    int d4 = it * 64 + lane;  // float4 index; d = d4*4
    float4 v = xr[d4];
    bf16x4 ob;
    ob[0] = (bf16_t)v.x; ob[1] = (bf16_t)v.y;
    ob[2] = (bf16_t)v.z; ob[3] = (bf16_t)v.w;
    xbr[d4] = ob;
    const float4* wr = (const float4*)(Wg + (size_t)d4 * 32);  // 4 rows x 8
    float xs[4] = {v.x, v.y, v.z, v.w};
#pragma unroll
    for (int rr = 0; rr < 4; ++rr) {
      float4 wa = wr[rr * 2], wb = wr[rr * 2 + 1];
      acc[0] += xs[rr] * wa.x; acc[1] += xs[rr] * wa.y;
      acc[2] += xs[rr] * wa.z; acc[3] += xs[rr] * wa.w;
      acc[4] += xs[rr] * wb.x; acc[5] += xs[rr] * wb.y;
      acc[6] += xs[rr] * wb.z; acc[7] += xs[rr] * wb.w;
    }
  }
#pragma unroll
  for (int off = 32; off >= 1; off >>= 1) {
#pragma unroll
    for (int e = 0; e < 8; ++e) acc[e] += __shfl_xor(acc[e], off, 64);
  }
  if (lane == 0) {
#pragma unroll
    for (int e = 0; e < 8; ++e) acc[e] += bg[e];
    float m = acc[0];
#pragma unroll
    for (int e = 1; e < 8; ++e) m = fmaxf(m, acc[e]);
    float s = 0.f, ex[8];
#pragma unroll
    for (int e = 0; e < 8; ++e) { ex[e] = __expf(acc[e] - m); s += ex[e]; }
    float inv = 1.0f / s;
    float* gr = gates + (size_t)b * 8;
#pragma unroll
    for (int e = 0; e < 8; ++e) gr[e] = ex[e] * inv;
  }
}

// ---------------- We [E,D,O] fp32 -> WeT [E,O,D] bf16 (unchanged) ----------------
__global__ __launch_bounds__(256) void transpose_we(
    const float* __restrict__ We, bf16_t* __restrict__ WeT) {
  __shared__ float tile[64][65];
  const int e = blockIdx.z;
  const int d0 = blockIdx.y * 64, o0 = blockIdx.x * 64;
  const int tx = threadIdx.x & 63, ty = threadIdx.x >> 6;
  const float* src = We + (size_t)e * D_SZ * O_SZ;
#pragma unroll
  for (int i = 0; i < 16; ++i) {
    int d = ty + i * 4;
    tile[d][tx] = src[(size_t)(d0 + d) * O_SZ + o0 + tx];
  }
  __syncthreads();
  bf16_t* dst = WeT + (size_t)e * O_SZ * D_SZ;
#pragma unroll
  for (int i = 0; i < 16; ++i) {
    int o = ty + i * 4;
    dst[(size_t)(o0 + o) * D_SZ + d0 + tx] = (bf16_t)tile[tx][o];
  }
}

// ---------------- fused expert GEMM + gate combine (ring-3, counted vmcnt) ----------------
__device__ __forceinline__ void gl16(const bf16_t* g, const bf16_t* l) {
  __builtin_amdgcn_global_load_lds(
      (const __attribute__((address_space(1))) void*)g,
      (__attribute__((address_space(3))) void*)l, 16, 0, 0);
}

__global__ __launch_bounds__(512, 2) void moe_gemm(
    const bf16_t* __restrict__ xb,    // [B, D] bf16
    const bf16_t* __restrict__ wet,   // [E, O, D] bf16
    const float* __restrict__ gates,  // [B, E]
    const float* __restrict__ be,     // [E, O]
    float* __restrict__ out)          // [B, O]
{
  // ring-3 double... triple-buffer: compute t from buf t%3, stage t+2 into (t+2)%3
  __shared__ bf16_t lA[3][BM * BK];   // 3 x 32 KB
  __shared__ bf16_t lB[3][BN * BK];   // 3 x 16 KB
  __shared__ float  lG[BM * 9];       // gates, padded stride 9 (bank spread)
  __shared__ float  lBe[E_SZ * BN];   // be tile: keeps loop free of global loads

  const int tid = threadIdx.x;
  const int w = tid >> 6, lane = tid & 63;
  const int b0 = blockIdx.y * BM;
  const int o0 = blockIdx.x * BN;
  const int wm = (w >> 1) * 64, wn = (w & 1) * 64;  // 4x2 wave grid, 64x64 per wave
  const int m16 = lane & 15, q = lane >> 4;

  // ---- prologue: gates + be into LDS (no global loads inside main loop!) ----
  {
    float4 g4 = ((const float4*)(gates + (size_t)b0 * 8))[tid];
    int gr = tid >> 1, gc = (tid & 1) * 4;
    lG[gr * 9 + gc + 0] = g4.x; lG[gr * 9 + gc + 1] = g4.y;
    lG[gr * 9 + gc + 2] = g4.z; lG[gr * 9 + gc + 3] = g4.w;
#pragma unroll
    for (int p = 0; p < 2; ++p) {
      int idx = tid + p * 512;
      lBe[idx] = be[(size_t)(idx >> 7) * O_SZ + o0 + (idx & 127)];
    }
  }

  // ---- per-lane staging constants ----
  // LDS dest is linear (wave base + lane*16); swizzle applied on the GLOBAL side:
  // phys 16B slot s at row r holds logical slot s^(r&7)  (read applies same XOR)
  const bf16_t* aptr[4]; int aoffL[4];
#pragma unroll
  for (int j = 0; j < 4; ++j) {
    int g0 = w * 64 + 512 * j;            // wave-uniform base granule
    int row = (g0 >> 3) + (lane >> 3);    // 8 granules (128B) per 64-col row
    int ls = (lane & 7) ^ (row & 7);      // logical slot this lane must fetch
    aptr[j] = xb + (size_t)(b0 + row) * D_SZ + ls * 8;
    aoffL[j] = g0 * 8;                    // LDS elem offset (granule*8 bf16)
  }
  const bf16_t* bptr[2]; int boffL[2];
#pragma unroll
  for (int j = 0; j < 2; ++j) {
    int g0 = w * 64 + 512 * j;
    int row = (g0 >> 3) + (lane >> 3);
    int ls = (lane & 7) ^ (row & 7);
    bptr[j] = wet + (size_t)(o0 + row) * D_SZ + ls * 8;
    boffL[j] = g0 * 8;
  }

#define STAGE(t_, buf_) do {                                                   \
    const int kk_ = ((t_) & 15) << 6;                                          \
    const size_t eo_ = (((size_t)((t_) >> 4)) << 20) + kk_;                    \
    _Pragma("unroll")                                                          \
    for (int js = 0; js < 4; ++js) gl16(aptr[js] + kk_, &lA[buf_][0] + aoffL[js]); \
    _Pragma("unroll")                                                          \
    for (int js = 0; js < 2; ++js) gl16(bptr[js] + eo_, &lB[buf_][0] + boffL[js]); \
  } while (0)

  f32x4 acc[4][4], outAcc[4][4];
#pragma unroll
  for (int i = 0; i < 4; ++i)
#pragma unroll
    for (int j = 0; j < 4; ++j) {
      acc[i][j] = f32x4{0.f, 0.f, 0.f, 0.f};
      outAcc[i][j] = f32x4{0.f, 0.f, 0.f, 0.f};
    }

  STAGE(0, 0);
  STAGE(1, 1);
  // drain own lG/lBe ds_writes so the first loop barrier publishes them
  asm volatile("s_waitcnt lgkmcnt(0)" ::: "memory");

  // per K-step body: 16 ds_read_b128 + 32 MFMA per wave; every read is consumed
  // by an MFMA in-iteration, so lgkm waits drain all LDS reads before the next
  // barrier -> single barrier per K-step is race-free.
#define BODY(cur_) do {                                                        \
    const bf16_t* la_ = &lA[cur_][0];                                          \
    const bf16_t* lb_ = &lB[cur_][0];                                          \
    bf16x8 bfr[4][2];                                                          \
    _Pragma("unroll")                                                          \
    for (int j = 0; j < 4; ++j) {                                              \
      int r = wn + j * 16 + m16;                                               \
      const char* rb = (const char*)lb_ + r * 128;                             \
      bfr[j][0] = *(const bf16x8*)(rb + (((q) ^ (r & 7)) << 4));               \
      bfr[j][1] = *(const bf16x8*)(rb + (((4 | q) ^ (r & 7)) << 4));           \
    }                                                                          \
    _Pragma("unroll")                                                          \
    for (int i = 0; i < 4; ++i) {                                              \
      int r = wm + i * 16 + m16;                                               \
      const char* ra = (const char*)la_ + r * 128;                             \
      bf16x8 a0 = *(const bf16x8*)(ra + (((q) ^ (r & 7)) << 4));               \
      bf16x8 a1 = *(const bf16x8*)(ra + (((4 | q) ^ (r & 7)) << 4));           \
      _Pragma("unroll")                                                        \
      for (int j = 0; j < 4; ++j) {                                            \
        acc[i][j] = __builtin_amdgcn_mfma_f32_16x16x32_bf16(                   \
            a0, bfr[j][0], acc[i][j], 0, 0, 0);                                \
        acc[i][j] = __builtin_amdgcn_mfma_f32_16x16x32_bf16(                   \
            a1, bfr[j][1], acc[i][j], 0, 0, 0);                                \
      }                                                                        \
    }                                                                          \
  } while (0)

  // C layout: col = lane&15, row = q*4+reg  (dtype-independent on gfx950)
#define COMBINE(e_) do {                                                       \
    float bec_[4];                                                             \
    _Pragma("unroll")                                                          \
    for (int j = 0; j < 4; ++j) bec_[j] = lBe[(e_) * BN + wn + j * 16 + m16];  \
    _Pragma("unroll")                                                          \
    for (int i = 0; i < 4; ++i) {                                              \
      _Pragma("unroll")                                                        \
      for (int rg = 0; rg < 4; ++rg) {                                         \
        float gv = lG[(wm + i * 16 + q * 4 + rg) * 9 + (e_)];                  \
        _Pragma("unroll")                                                      \
        for (int j = 0; j < 4; ++j) {                                          \
          outAcc[i][j][rg] += gv * (acc[i][j][rg] + bec_[j]);                  \
          acc[i][j][rg] = 0.f;                                                 \
        }                                                                      \
      }                                                                        \
    }                                                                          \
  } while (0)

  int cur = 0;
#pragma unroll 1
  for (int t = 0; t < NT - 1; ++t) {
    // own 6 loads of tile t retire; tile t+1's 6 stay in flight ACROSS the barrier
    asm volatile("s_waitcnt vmcnt(6)" ::: "memory");
    __builtin_amdgcn_s_barrier();
    asm volatile("" ::: "memory");
    if (t <= NT - 3) {
      int nb = cur + 2; if (nb >= 3) nb -= 3;
      STAGE(t + 2, nb);
    }
    BODY(cur);
    if ((t & 15) == 15) COMBINE(t >> 4);  // expert boundary every 16 K-steps
    ++cur; if (cur == 3) cur = 0;
  }
  asm volatile("s_waitcnt vmcnt(0)" ::: "memory");  // epilogue drain (once)
  __builtin_amdgcn_s_barrier();
  asm volatile("" ::: "memory");
  BODY(cur);
  COMBINE(7);

  // ---- epilogue: store combined output ----
#pragma unroll
  for (int i = 0; i < 4; ++i)
#pragma unroll
    for (int rg = 0; rg < 4; ++rg) {
      float* orow = out + (size_t)(b0 + wm + i * 16 + q * 4 + rg) * O_SZ
                    + o0 + wn + m16;
#pragma unroll
      for (int j = 0; j < 4; ++j) orow[j * 16] = outAcc[i][j][rg];
    }
}

extern "C" void kernel_launch(void* const* d_in, const int* in_sizes, int n_in,
                              void* d_out, int out_size, void* d_ws, size_t ws_size,
                              hipStream_t stream) {
  const float* x  = (const float*)d_in[0];
  const float* Wg = (const float*)d_in[1];
  const float* bg = (const float*)d_in[2];
  const float* We = (const float*)d_in[3];
  const float* be = (const float*)d_in[4];
  float* out = (float*)d_out;

  char* ws = (char*)d_ws;
  float*  gates = (float*)ws;                             // 256 KB
  bf16_t* xb    = (bf16_t*)(ws + (1 << 18));              // 16 MB
  bf16_t* wet   = (bf16_t*)(ws + (1 << 18) + (1 << 24));  // 16 MB

  gating_cvt_kernel<<<B_SZ / 4, 256, 0, stream>>>(x, Wg, bg, gates, xb);
  transpose_we<<<dim3(O_SZ / 64, D_SZ / 64, E_SZ), 256, 0, stream>>>(We, wet);
  moe_gemm<<<dim3(O_SZ / BN, B_SZ / BM), 512, 0, stream>>>(xb, wet, gates, be, out);
}

// Round 2
// 292.199 us; speedup vs baseline: 1.0347x; 1.0347x over previous
//
#include <hip/hip_runtime.h>
#include <hip/hip_bf16.h>
#include <stdint.h>

#define B_SZ 8192
#define D_SZ 1024
#define O_SZ 1024
#define E_SZ 8

#define BM 256
#define BN 128
#define BK 64
#define NT 128  // virtual K-steps: E_SZ * (D_SZ / BK)

typedef __bf16 bf16_t;
typedef __bf16 bf16x8 __attribute__((ext_vector_type(8)));
typedef __bf16 bf16x4 __attribute__((ext_vector_type(4)));
typedef float  f32x4  __attribute__((ext_vector_type(4)));

// ---------------- gating: softmax(x @ Wg + bg) fused with x fp32->bf16 ----------------
__global__ __launch_bounds__(256) void gating_cvt_kernel(
    const float* __restrict__ x, const float* __restrict__ Wg,
    const float* __restrict__ bg, float* __restrict__ gates,
    bf16_t* __restrict__ xb) {
  const int w = threadIdx.x >> 6, lane = threadIdx.x & 63;
  const int b = blockIdx.x * 4 + w;
  const float4* xr = (const float4*)(x + (size_t)b * D_SZ);
  bf16x4* xbr = (bf16x4*)(xb + (size_t)b * D_SZ);
  float acc[8];
#pragma unroll
  for (int e = 0; e < 8; ++e) acc[e] = 0.f;
#pragma unroll 1
  for (int it = 0; it < 4; ++it) {
    int d4 = it * 64 + lane;  // float4 index; d = d4*4
    float4 v = xr[d4];
    bf16x4 ob;
    ob[0] = (bf16_t)v.x; ob[1] = (bf16_t)v.y;
    ob[2] = (bf16_t)v.z; ob[3] = (bf16_t)v.w;
    xbr[d4] = ob;
    const float4* wr = (const float4*)(Wg + (size_t)d4 * 32);  // 4 rows x 8
    float xs[4] = {v.x, v.y, v.z, v.w};
#pragma unroll
    for (int rr = 0; rr < 4; ++rr) {
      float4 wa = wr[rr * 2], wb = wr[rr * 2 + 1];
      acc[0] += xs[rr] * wa.x; acc[1] += xs[rr] * wa.y;
      acc[2] += xs[rr] * wa.z; acc[3] += xs[rr] * wa.w;
      acc[4] += xs[rr] * wb.x; acc[5] += xs[rr] * wb.y;
      acc[6] += xs[rr] * wb.z; acc[7] += xs[rr] * wb.w;
    }
  }
#pragma unroll
  for (int off = 32; off >= 1; off >>= 1) {
#pragma unroll
    for (int e = 0; e < 8; ++e) acc[e] += __shfl_xor(acc[e], off, 64);
  }
  if (lane == 0) {
#pragma unroll
    for (int e = 0; e < 8; ++e) acc[e] += bg[e];
    float m = acc[0];
#pragma unroll
    for (int e = 1; e < 8; ++e) m = fmaxf(m, acc[e]);
    float s = 0.f, ex[8];
#pragma unroll
    for (int e = 0; e < 8; ++e) { ex[e] = __expf(acc[e] - m); s += ex[e]; }
    float inv = 1.0f / s;
    float* gr = gates + (size_t)b * 8;
#pragma unroll
    for (int e = 0; e < 8; ++e) gr[e] = ex[e] * inv;
  }
}

// ---------------- We [E,D,O] fp32 -> WeT [E,O,D] bf16 (unchanged) ----------------
__global__ __launch_bounds__(256) void transpose_we(
    const float* __restrict__ We, bf16_t* __restrict__ WeT) {
  __shared__ float tile[64][65];
  const int e = blockIdx.z;
  const int d0 = blockIdx.y * 64, o0 = blockIdx.x * 64;
  const int tx = threadIdx.x & 63, ty = threadIdx.x >> 6;
  const float* src = We + (size_t)e * D_SZ * O_SZ;
#pragma unroll
  for (int i = 0; i < 16; ++i) {
    int d = ty + i * 4;
    tile[d][tx] = src[(size_t)(d0 + d) * O_SZ + o0 + tx];
  }
  __syncthreads();
  bf16_t* dst = WeT + (size_t)e * O_SZ * D_SZ;
#pragma unroll
  for (int i = 0; i < 16; ++i) {
    int o = ty + i * 4;
    dst[(size_t)(o0 + o) * D_SZ + d0 + tx] = (bf16_t)tile[tx][o];
  }
}

// ---------------- fused expert GEMM + gate combine (ring-3, counted vmcnt) ----------------
__device__ __forceinline__ void gl16(const bf16_t* g, const bf16_t* l) {
  __builtin_amdgcn_global_load_lds(
      (const __attribute__((address_space(1))) void*)g,
      (__attribute__((address_space(3))) void*)l, 16, 0, 0);
}

__global__ __launch_bounds__(512, 2) void moe_gemm(
    const bf16_t* __restrict__ xb,    // [B, D] bf16
    const bf16_t* __restrict__ wet,   // [E, O, D] bf16
    const float* __restrict__ gates,  // [B, E]
    const float* __restrict__ be,     // [E, O]
    float* __restrict__ out)          // [B, O]
{
  // ring-3 buffers: compute t from buf t%3, stage t+2 into (t+2)%3
  __shared__ bf16_t lA[3][BM * BK];   // 3 x 32 KB
  __shared__ bf16_t lB[3][BN * BK];   // 3 x 16 KB
  __shared__ float  lG[BM * 9];       // gates, padded stride 9 (bank spread)
  __shared__ float  lBe[E_SZ * BN];   // be tile: keeps loop free of global loads

  const int tid = threadIdx.x;
  const int w = tid >> 6, lane = tid & 63;

  // ---- XCD-locality remap ----
  // Default round-robin puts flat%8 on XCD flat%8. Launched grid is
  // (8 o-tiles, 32 b-tiles): flat = o + 8*b, so default co-locates all 32
  // blocks of one o-slice per XCD -> wet L2-resident, BUT the 32 distinct
  // 0.5MB xb slices (16 MB) thrash L2 and every per-expert xb re-read (8x)
  // goes to L3/HBM: 533 MB fetch ~= whole kernel time.
  // Remap: XCD x gets 4 b-tiles x 8 o-tiles -> xb working set 2 MB (L2-hit
  // re-reads) and wet streams a ~128KB/step window shared by 4 blocks.
  const int flat = blockIdx.x + (blockIdx.y << 3);  // gridDim.x == 8
  const int xcd = flat & 7, slot = flat >> 3;
  const int bt = (xcd << 2) + (slot & 3);  // b-tile 0..31
  const int ot = slot >> 2;                // o-tile 0..7
  const int b0 = bt * BM;
  const int o0 = ot * BN;

  const int wm = (w >> 1) * 64, wn = (w & 1) * 64;  // 4x2 wave grid, 64x64 per wave
  const int m16 = lane & 15, q = lane >> 4;

  // ---- prologue: gates + be into LDS (no global loads inside main loop!) ----
  {
    float4 g4 = ((const float4*)(gates + (size_t)b0 * 8))[tid];
    int gr = tid >> 1, gc = (tid & 1) * 4;
    lG[gr * 9 + gc + 0] = g4.x; lG[gr * 9 + gc + 1] = g4.y;
    lG[gr * 9 + gc + 2] = g4.z; lG[gr * 9 + gc + 3] = g4.w;
#pragma unroll
    for (int p = 0; p < 2; ++p) {
      int idx = tid + p * 512;
      lBe[idx] = be[(size_t)(idx >> 7) * O_SZ + o0 + (idx & 127)];
    }
  }

  // ---- per-lane staging constants ----
  // LDS dest is linear (wave base + lane*16); swizzle applied on the GLOBAL side:
  // phys 16B slot s at row r holds logical slot s^(r&7)  (read applies same XOR)
  const bf16_t* aptr[4]; int aoffL[4];
#pragma unroll
  for (int j = 0; j < 4; ++j) {
    int g0 = w * 64 + 512 * j;            // wave-uniform base granule
    int row = (g0 >> 3) + (lane >> 3);    // 8 granules (128B) per 64-col row
    int ls = (lane & 7) ^ (row & 7);      // logical slot this lane must fetch
    aptr[j] = xb + (size_t)(b0 + row) * D_SZ + ls * 8;
    aoffL[j] = g0 * 8;                    // LDS elem offset (granule*8 bf16)
  }
  const bf16_t* bptr[2]; int boffL[2];
#pragma unroll
  for (int j = 0; j < 2; ++j) {
    int g0 = w * 64 + 512 * j;
    int row = (g0 >> 3) + (lane >> 3);
    int ls = (lane & 7) ^ (row & 7);
    bptr[j] = wet + (size_t)(o0 + row) * D_SZ + ls * 8;
    boffL[j] = g0 * 8;
  }

#define STAGE(t_, buf_) do {                                                   \
    const int kk_ = ((t_) & 15) << 6;                                          \
    const size_t eo_ = (((size_t)((t_) >> 4)) << 20) + kk_;                    \
    _Pragma("unroll")                                                          \
    for (int js = 0; js < 4; ++js) gl16(aptr[js] + kk_, &lA[buf_][0] + aoffL[js]); \
    _Pragma("unroll")                                                          \
    for (int js = 0; js < 2; ++js) gl16(bptr[js] + eo_, &lB[buf_][0] + boffL[js]); \
  } while (0)

  f32x4 acc[4][4], outAcc[4][4];
#pragma unroll
  for (int i = 0; i < 4; ++i)
#pragma unroll
    for (int j = 0; j < 4; ++j) {
      acc[i][j] = f32x4{0.f, 0.f, 0.f, 0.f};
      outAcc[i][j] = f32x4{0.f, 0.f, 0.f, 0.f};
    }

  STAGE(0, 0);
  STAGE(1, 1);
  // drain own lG/lBe ds_writes so the first loop barrier publishes them
  asm volatile("s_waitcnt lgkmcnt(0)" ::: "memory");

  // per K-step body: 16 ds_read_b128 + 32 MFMA per wave; every read is consumed
  // by an MFMA in-iteration, so lgkm waits drain all LDS reads before the next
  // barrier -> single barrier per K-step is race-free.
#define BODY(cur_) do {                                                        \
    const bf16_t* la_ = &lA[cur_][0];                                          \
    const bf16_t* lb_ = &lB[cur_][0];                                          \
    bf16x8 bfr[4][2];                                                          \
    _Pragma("unroll")                                                          \
    for (int j = 0; j < 4; ++j) {                                              \
      int r = wn + j * 16 + m16;                                               \
      const char* rb = (const char*)lb_ + r * 128;                             \
      bfr[j][0] = *(const bf16x8*)(rb + (((q) ^ (r & 7)) << 4));               \
      bfr[j][1] = *(const bf16x8*)(rb + (((4 | q) ^ (r & 7)) << 4));           \
    }                                                                          \
    _Pragma("unroll")                                                          \
    for (int i = 0; i < 4; ++i) {                                              \
      int r = wm + i * 16 + m16;                                               \
      const char* ra = (const char*)la_ + r * 128;                             \
      bf16x8 a0 = *(const bf16x8*)(ra + (((q) ^ (r & 7)) << 4));               \
      bf16x8 a1 = *(const bf16x8*)(ra + (((4 | q) ^ (r & 7)) << 4));           \
      _Pragma("unroll")                                                        \
      for (int j = 0; j < 4; ++j) {                                            \
        acc[i][j] = __builtin_amdgcn_mfma_f32_16x16x32_bf16(                   \
            a0, bfr[j][0], acc[i][j], 0, 0, 0);                                \
        acc[i][j] = __builtin_amdgcn_mfma_f32_16x16x32_bf16(                   \
            a1, bfr[j][1], acc[i][j], 0, 0, 0);                                \
      }                                                                        \
    }                                                                          \
  } while (0)

  // C layout: col = lane&15, row = q*4+reg  (dtype-independent on gfx950)
#define COMBINE(e_) do {                                                       \
    float bec_[4];                                                             \
    _Pragma("unroll")                                                          \
    for (int j = 0; j < 4; ++j) bec_[j] = lBe[(e_) * BN + wn + j * 16 + m16];  \
    _Pragma("unroll")                                                          \
    for (int i = 0; i < 4; ++i) {                                              \
      _Pragma("unroll")                                                        \
      for (int rg = 0; rg < 4; ++rg) {                                         \
        float gv = lG[(wm + i * 16 + q * 4 + rg) * 9 + (e_)];                  \
        _Pragma("unroll")                                                      \
        for (int j = 0; j < 4; ++j) {                                          \
          outAcc[i][j][rg] += gv * (acc[i][j][rg] + bec_[j]);                  \
          acc[i][j][rg] = 0.f;                                                 \
        }                                                                      \
      }                                                                        \
    }                                                                          \
  } while (0)

  int cur = 0;
#pragma unroll 1
  for (int t = 0; t < NT - 1; ++t) {
    // own 6 loads of tile t retire; tile t+1's 6 stay in flight ACROSS the barrier
    asm volatile("s_waitcnt vmcnt(6)" ::: "memory");
    __builtin_amdgcn_s_barrier();
    asm volatile("" ::: "memory");
    if (t <= NT - 3) {
      int nb = cur + 2; if (nb >= 3) nb -= 3;
      STAGE(t + 2, nb);
    }
    BODY(cur);
    if ((t & 15) == 15) COMBINE(t >> 4);  // expert boundary every 16 K-steps
    ++cur; if (cur == 3) cur = 0;
  }
  asm volatile("s_waitcnt vmcnt(0)" ::: "memory");  // epilogue drain (once)
  __builtin_amdgcn_s_barrier();
  asm volatile("" ::: "memory");
  BODY(cur);
  COMBINE(7);

  // ---- epilogue: store combined output ----
#pragma unroll
  for (int i = 0; i < 4; ++i)
#pragma unroll
    for (int rg = 0; rg < 4; ++rg) {
      float* orow = out + (size_t)(b0 + wm + i * 16 + q * 4 + rg) * O_SZ
                    + o0 + wn + m16;
#pragma unroll
      for (int j = 0; j < 4; ++j) orow[j * 16] = outAcc[i][j][rg];
    }
}

extern "C" void kernel_launch(void* const* d_in, const int* in_sizes, int n_in,
                              void* d_out, int out_size, void* d_ws, size_t ws_size,
                              hipStream_t stream) {
  const float* x  = (const float*)d_in[0];
  const float* Wg = (const float*)d_in[1];
  const float* bg = (const float*)d_in[2];
  const float* We = (const float*)d_in[3];
  const float* be = (const float*)d_in[4];
  float* out = (float*)d_out;

  char* ws = (char*)d_ws;
  float*  gates = (float*)ws;                             // 256 KB
  bf16_t* xb    = (bf16_t*)(ws + (1 << 18));              // 16 MB
  bf16_t* wet   = (bf16_t*)(ws + (1 << 18) + (1 << 24));  // 16 MB

  gating_cvt_kernel<<<B_SZ / 4, 256, 0, stream>>>(x, Wg, bg, gates, xb);
  transpose_we<<<dim3(O_SZ / 64, D_SZ / 64, E_SZ), 256, 0, stream>>>(We, wet);
  moe_gemm<<<dim3(O_SZ / BN, B_SZ / BM), 512, 0, stream>>>(xb, wet, gates, be, out);
}

// Round 3
// 256.927 us; speedup vs baseline: 1.1768x; 1.1373x over previous
//
#include <hip/hip_runtime.h>
#include <hip/hip_bf16.h>
#include <stdint.h>

#define B_SZ 8192
#define D_SZ 1024
#define O_SZ 1024
#define E_SZ 8

#define BM 256
#define BN 128
#define BK 64
#define NT 128  // virtual K-steps: E_SZ * (D_SZ / BK)

typedef __bf16 bf16_t;
typedef __bf16 bf16x8 __attribute__((ext_vector_type(8)));
typedef __bf16 bf16x4 __attribute__((ext_vector_type(4)));
typedef float  f32x4  __attribute__((ext_vector_type(4)));

// ---------------- merged prep: gating+cvt (blocks 0..2047) | We transpose (2048..4095) ----------------
__global__ __launch_bounds__(256) void prep_kernel(
    const float* __restrict__ x, const float* __restrict__ Wg,
    const float* __restrict__ bg, const float* __restrict__ We,
    float* __restrict__ gates, bf16_t* __restrict__ xb,
    bf16_t* __restrict__ wet) {
  __shared__ float tile[64][65];
  const int bid = blockIdx.x;
  if (bid < 2048) {
    // ---- gating: softmax(x @ Wg + bg) fused with x fp32->bf16 ----
    const int w = threadIdx.x >> 6, lane = threadIdx.x & 63;
    const int b = bid * 4 + w;
    const float4* xr = (const float4*)(x + (size_t)b * D_SZ);
    bf16x4* xbr = (bf16x4*)(xb + (size_t)b * D_SZ);
    float acc[8];
#pragma unroll
    for (int e = 0; e < 8; ++e) acc[e] = 0.f;
#pragma unroll 1
    for (int it = 0; it < 4; ++it) {
      int d4 = it * 64 + lane;  // float4 index; d = d4*4
      float4 v = xr[d4];
      bf16x4 ob;
      ob[0] = (bf16_t)v.x; ob[1] = (bf16_t)v.y;
      ob[2] = (bf16_t)v.z; ob[3] = (bf16_t)v.w;
      xbr[d4] = ob;
      const float4* wr = (const float4*)(Wg + (size_t)d4 * 32);  // 4 rows x 8
      float xs[4] = {v.x, v.y, v.z, v.w};
#pragma unroll
      for (int rr = 0; rr < 4; ++rr) {
        float4 wa = wr[rr * 2], wb = wr[rr * 2 + 1];
        acc[0] += xs[rr] * wa.x; acc[1] += xs[rr] * wa.y;
        acc[2] += xs[rr] * wa.z; acc[3] += xs[rr] * wa.w;
        acc[4] += xs[rr] * wb.x; acc[5] += xs[rr] * wb.y;
        acc[6] += xs[rr] * wb.z; acc[7] += xs[rr] * wb.w;
      }
    }
#pragma unroll
    for (int off = 32; off >= 1; off >>= 1) {
#pragma unroll
      for (int e = 0; e < 8; ++e) acc[e] += __shfl_xor(acc[e], off, 64);
    }
    if (lane == 0) {
#pragma unroll
      for (int e = 0; e < 8; ++e) acc[e] += bg[e];
      float m = acc[0];
#pragma unroll
      for (int e = 1; e < 8; ++e) m = fmaxf(m, acc[e]);
      float s = 0.f, ex[8];
#pragma unroll
      for (int e = 0; e < 8; ++e) { ex[e] = __expf(acc[e] - m); s += ex[e]; }
      float inv = 1.0f / s;
      float* gr = gates + (size_t)b * 8;
#pragma unroll
      for (int e = 0; e < 8; ++e) gr[e] = ex[e] * inv;
    }
  } else {
    // ---- We [E,D,O] fp32 -> WeT [E,O,D] bf16 ----
    const int bt = bid - 2048;
    const int e = bt >> 8;
    const int d0 = ((bt >> 4) & 15) * 64, o0 = (bt & 15) * 64;
    const int tx = threadIdx.x & 63, ty = threadIdx.x >> 6;
    const float* src = We + (size_t)e * D_SZ * O_SZ;
#pragma unroll
    for (int i = 0; i < 16; ++i) {
      int d = ty + i * 4;
      tile[d][tx] = src[(size_t)(d0 + d) * O_SZ + o0 + tx];
    }
    __syncthreads();
    bf16_t* dst = wet + (size_t)e * O_SZ * D_SZ;
#pragma unroll
    for (int i = 0; i < 16; ++i) {
      int o = ty + i * 4;
      dst[(size_t)(o0 + o) * D_SZ + d0 + tx] = (bf16_t)tile[tx][o];
    }
  }
}

// ---------------- fused expert GEMM + gate combine (ring-3, counted vmcnt) ----------------
__device__ __forceinline__ void gl16(const bf16_t* g, const bf16_t* l) {
  __builtin_amdgcn_global_load_lds(
      (const __attribute__((address_space(1))) void*)g,
      (__attribute__((address_space(3))) void*)l, 16, 0, 0);
}

__global__ __launch_bounds__(512, 2) void moe_gemm(
    const bf16_t* __restrict__ xb,    // [B, D] bf16
    const bf16_t* __restrict__ wet,   // [E, O, D] bf16
    const float* __restrict__ gates,  // [B, E]
    const float* __restrict__ be,     // [E, O]
    float* __restrict__ out)          // [B, O]
{
  // ring-3 buffers: compute t from buf t%3, stage t+2 into (t+2)%3
  __shared__ bf16_t lA[3][BM * BK];   // 3 x 32 KB
  __shared__ bf16_t lB[3][BN * BK];   // 3 x 16 KB
  __shared__ float  lG[BM * 9];       // gates, padded stride 9 (bank spread)
  __shared__ float  lBe[E_SZ * BN];   // be tile: keeps loop free of global loads

  const int tid = threadIdx.x;
  const int w = tid >> 6, lane = tid & 63;

  // ---- XCD-locality remap (round 2: FETCH 533->97 MB) ----
  const int flat = blockIdx.x + (blockIdx.y << 3);  // gridDim.x == 8
  const int xcd = flat & 7, slot = flat >> 3;
  const int bt = (xcd << 2) + (slot & 3);  // b-tile 0..31
  const int ot = slot >> 2;                // o-tile 0..7
  const int b0 = bt * BM;
  const int o0 = ot * BN;

  const int wm = (w >> 1) * 64, wn = (w & 1) * 64;  // 4x2 wave grid, 64x64 per wave
  const int m16 = lane & 15, q = lane >> 4;

  // ---- prologue: gates + be into LDS (no global loads inside main loop!) ----
  {
    float4 g4 = ((const float4*)(gates + (size_t)b0 * 8))[tid];
    int gr = tid >> 1, gc = (tid & 1) * 4;
    lG[gr * 9 + gc + 0] = g4.x; lG[gr * 9 + gc + 1] = g4.y;
    lG[gr * 9 + gc + 2] = g4.z; lG[gr * 9 + gc + 3] = g4.w;
#pragma unroll
    for (int p = 0; p < 2; ++p) {
      int idx = tid + p * 512;
      lBe[idx] = be[(size_t)(idx >> 7) * O_SZ + o0 + (idx & 127)];
    }
  }

  // ---- per-lane staging constants ----
  // LDS dest is linear (wave base + lane*16); swizzle applied on the GLOBAL side:
  // phys 16B slot s at row r holds logical slot s^(r&7)  (read applies same XOR)
  const bf16_t* aptr[4]; int aoffL[4];
#pragma unroll
  for (int j = 0; j < 4; ++j) {
    int g0 = w * 64 + 512 * j;            // wave-uniform base granule
    int row = (g0 >> 3) + (lane >> 3);    // 8 granules (128B) per 64-col row
    int ls = (lane & 7) ^ (row & 7);      // logical slot this lane must fetch
    aptr[j] = xb + (size_t)(b0 + row) * D_SZ + ls * 8;
    aoffL[j] = g0 * 8;                    // LDS elem offset (granule*8 bf16)
  }
  const bf16_t* bptr[2]; int boffL[2];
#pragma unroll
  for (int j = 0; j < 2; ++j) {
    int g0 = w * 64 + 512 * j;
    int row = (g0 >> 3) + (lane >> 3);
    int ls = (lane & 7) ^ (row & 7);
    bptr[j] = wet + (size_t)(o0 + row) * D_SZ + ls * 8;
    boffL[j] = g0 * 8;
  }

  // ---- hoisted per-lane LDS read byte-offsets (loop-invariant) ----
  // read A: r = wm + i*16 + m16; byte = r*128 + ((h4|q)^(r&7))<<4; r&7 == m16&7
  const int xk = m16 & 7;
  const int offA0 = (wm + m16) * 128 + ((q ^ xk) << 4);
  const int offA1 = (wm + m16) * 128 + (((4 | q) ^ xk) << 4);
  const int offB0 = (wn + m16) * 128 + ((q ^ xk) << 4);
  const int offB1 = (wn + m16) * 128 + (((4 | q) ^ xk) << 4);

#define STAGE(t_, buf_) do {                                                   \
    const int kk_ = ((t_) & 15) << 6;                                          \
    const size_t eo_ = (((size_t)((t_) >> 4)) << 20) + kk_;                    \
    _Pragma("unroll")                                                          \
    for (int js = 0; js < 4; ++js) gl16(aptr[js] + kk_, &lA[buf_][0] + aoffL[js]); \
    _Pragma("unroll")                                                          \
    for (int js = 0; js < 2; ++js) gl16(bptr[js] + eo_, &lB[buf_][0] + boffL[js]); \
  } while (0)

  f32x4 acc[4][4], outAcc[4][4];
#pragma unroll
  for (int i = 0; i < 4; ++i)
#pragma unroll
    for (int j = 0; j < 4; ++j) {
      acc[i][j] = f32x4{0.f, 0.f, 0.f, 0.f};
      outAcc[i][j] = f32x4{0.f, 0.f, 0.f, 0.f};
    }

  STAGE(0, 0);
  STAGE(1, 1);
  // drain own lG/lBe ds_writes so the first loop barrier publishes them
  asm volatile("s_waitcnt lgkmcnt(0)" ::: "memory");

  // 2-phase body: per k-half {4 B-reads + 4 A-reads -> 16 MFMA under setprio}.
  // Every ds_read is consumed by an MFMA in-iteration, so compiler lgkm waits
  // drain all LDS reads before the next barrier -> single barrier per K-step.
#define BODY(cur_) do {                                                        \
    const char* la_ = (const char*)(&lA[cur_][0]);                             \
    const char* lb_ = (const char*)(&lB[cur_][0]);                             \
    bf16x8 a_[4], b_[4];                                                       \
    _Pragma("unroll")                                                          \
    for (int j = 0; j < 4; ++j) b_[j] = *(const bf16x8*)(lb_ + offB0 + j * 2048); \
    _Pragma("unroll")                                                          \
    for (int i = 0; i < 4; ++i) a_[i] = *(const bf16x8*)(la_ + offA0 + i * 2048); \
    __builtin_amdgcn_s_setprio(1);                                             \
    _Pragma("unroll")                                                          \
    for (int i = 0; i < 4; ++i)                                                \
      _Pragma("unroll")                                                        \
      for (int j = 0; j < 4; ++j)                                              \
        acc[i][j] = __builtin_amdgcn_mfma_f32_16x16x32_bf16(                   \
            a_[i], b_[j], acc[i][j], 0, 0, 0);                                 \
    __builtin_amdgcn_s_setprio(0);                                             \
    _Pragma("unroll")                                                          \
    for (int j = 0; j < 4; ++j) b_[j] = *(const bf16x8*)(lb_ + offB1 + j * 2048); \
    _Pragma("unroll")                                                          \
    for (int i = 0; i < 4; ++i) a_[i] = *(const bf16x8*)(la_ + offA1 + i * 2048); \
    __builtin_amdgcn_s_setprio(1);                                             \
    _Pragma("unroll")                                                          \
    for (int i = 0; i < 4; ++i)                                                \
      _Pragma("unroll")                                                        \
      for (int j = 0; j < 4; ++j)                                              \
        acc[i][j] = __builtin_amdgcn_mfma_f32_16x16x32_bf16(                   \
            a_[i], b_[j], acc[i][j], 0, 0, 0);                                 \
    __builtin_amdgcn_s_setprio(0);                                             \
  } while (0)

  // C layout: col = lane&15, row = q*4+reg  (dtype-independent on gfx950)
#define COMBINE(e_) do {                                                       \
    float bec_[4];                                                             \
    _Pragma("unroll")                                                          \
    for (int j = 0; j < 4; ++j) bec_[j] = lBe[(e_) * BN + wn + j * 16 + m16];  \
    _Pragma("unroll")                                                          \
    for (int i = 0; i < 4; ++i) {                                              \
      _Pragma("unroll")                                                        \
      for (int rg = 0; rg < 4; ++rg) {                                         \
        float gv = lG[(wm + i * 16 + q * 4 + rg) * 9 + (e_)];                  \
        _Pragma("unroll")                                                      \
        for (int j = 0; j < 4; ++j) {                                          \
          outAcc[i][j][rg] += gv * (acc[i][j][rg] + bec_[j]);                  \
          acc[i][j][rg] = 0.f;                                                 \
        }                                                                      \
      }                                                                        \
    }                                                                          \
  } while (0)

  // one K-step; cur_/nb_ are compile-time after manual unroll-3
#define STEP_S(t_, cur_, nb_) do {                                             \
    asm volatile("s_waitcnt vmcnt(6)" ::: "memory");                           \
    __builtin_amdgcn_s_barrier();                                              \
    asm volatile("" ::: "memory");                                             \
    STAGE((t_) + 2, nb_);                                                      \
    BODY(cur_);                                                                \
    if (((t_) & 15) == 15) COMBINE((t_) >> 4);                                 \
  } while (0)

#pragma unroll 1
  for (int t3 = 0; t3 < 126; t3 += 3) {
    STEP_S(t3 + 0, 0, 2);
    STEP_S(t3 + 1, 1, 0);
    STEP_S(t3 + 2, 2, 1);
  }
  // t = 126: no stage (tiles 0..127 all staged)
  asm volatile("s_waitcnt vmcnt(6)" ::: "memory");
  __builtin_amdgcn_s_barrier();
  asm volatile("" ::: "memory");
  BODY(0);
  // t = 127: final tile in buf 1
  asm volatile("s_waitcnt vmcnt(0)" ::: "memory");
  __builtin_amdgcn_s_barrier();
  asm volatile("" ::: "memory");
  BODY(1);
  COMBINE(7);

  // ---- epilogue: store combined output ----
#pragma unroll
  for (int i = 0; i < 4; ++i)
#pragma unroll
    for (int rg = 0; rg < 4; ++rg) {
      float* orow = out + (size_t)(b0 + wm + i * 16 + q * 4 + rg) * O_SZ
                    + o0 + wn + m16;
#pragma unroll
      for (int j = 0; j < 4; ++j) orow[j * 16] = outAcc[i][j][rg];
    }
}

extern "C" void kernel_launch(void* const* d_in, const int* in_sizes, int n_in,
                              void* d_out, int out_size, void* d_ws, size_t ws_size,
                              hipStream_t stream) {
  const float* x  = (const float*)d_in[0];
  const float* Wg = (const float*)d_in[1];
  const float* bg = (const float*)d_in[2];
  const float* We = (const float*)d_in[3];
  const float* be = (const float*)d_in[4];
  float* out = (float*)d_out;

  char* ws = (char*)d_ws;
  float*  gates = (float*)ws;                             // 256 KB
  bf16_t* xb    = (bf16_t*)(ws + (1 << 18));              // 16 MB
  bf16_t* wet   = (bf16_t*)(ws + (1 << 18) + (1 << 24));  // 16 MB

  prep_kernel<<<4096, 256, 0, stream>>>(x, Wg, bg, We, gates, xb, wet);
  moe_gemm<<<dim3(O_SZ / BN, B_SZ / BM), 512, 0, stream>>>(xb, wet, gates, be, out);
}